// Round 10
// baseline (94.460 us; speedup 1.0000x reference)
//
#include <hip/hip_runtime.h>
#include <hip/hip_fp16.h>

#define VOL    256
#define NPROJ  256
#define NDET   384
#define NS     256
#define NBATCH 2
#define QST    259                 // quarter texture row stride in dwords (259%32=3)
#define QR     69                  // V-rows staged per quarter (span+margins)
#define QDWP   17872               // QR*QST=17871, padded to uint4 multiple
#define QV4    (QDWP / 4)          // 4468 uint4 = 71,488 B LDS -> 2 blocks/CU
#define TPB    768                 // 12 waves/block; 1024 blocks -> 24 waves/CU

typedef _Float16 hvec2 __attribute__((ext_vector_type(2)));

// y-quarter bases: quarter h covers Y in [c_h, c_{h+1}), c = {0,65,129,193,257};
// staged V-rows are base_h + rowl, base_h = c_h - 2 (2-row slop margin).
__device__ __constant__ int c_base[4] = {-2, 63, 127, 191};

// Vertical-pair fp16 texture builder:
//   dst[(b*4+h)*QDWP + rowl*QST + c] = half2{ P(uy,c), P(uy+1,c) },
//   uy = c_base[h] + rowl,  P(y,x) = img[y-1][x-1] (zero outside).
__global__ void pad_build_kernel(const float* __restrict__ src, uint* __restrict__ dst) {
    int idx = blockIdx.x * blockDim.x + threadIdx.x;   // over NBATCH*4*QDWP
    if (idx >= NBATCH * 4 * QDWP) return;
    int bh = idx / QDWP;                               // b*4+h
    int dd = idx - bh * QDWP;
    uint val = 0u;
    if (dd < QR * QST) {
        int rowl = dd / QST;
        int c    = dd - rowl * QST;                    // texture col, valid 0..257
        int uy   = c_base[bh & 3] + rowl;
        int r0   = uy - 1;                             // img row of top tap
        int cc   = c - 1;                              // img col
        const float* im = src + ((bh >> 2) << 16);
        float v0 = 0.0f, v1 = 0.0f;
        if ((unsigned)cc < 256u && c < 258) {
            if ((unsigned)r0 < 256u)       v0 = im[(r0 << 8) + cc];
            if ((unsigned)(r0 + 1) < 256u) v1 = im[((r0 + 1) << 8) + cc];
        }
        __half2 h2 = __floats2half2_rn(v0, v1);        // low=row uy, high=row uy+1
        val = *reinterpret_cast<uint*>(&h2);
    }
    dst[idx] = val;
}

// 4 blocks per 768-ray group, one y-quarter each; exact complementary s-split
// at Y = 65/129/193; partials atomicAdd'ed into zeroed out.
__global__ __launch_bounds__(TPB) void fanproj_kernel(const uint4* __restrict__ G,
                                                      float* __restrict__ out) {
    __shared__ __align__(16) uint sV[QDWP];
    uint4* s4 = reinterpret_cast<uint4*>(sV);

    int tid = threadIdx.x;
    int h   = blockIdx.x & 3;
    int grp = blockIdx.x >> 2;
    int ray = grp * TPB + tid;                         // b*P*D + p*D + d
    int b   = grp >> 7;                                // 128 groups per batch

    // contiguous uint4 stage of this (batch, quarter) texture
    {
        const uint4* gb = G + (size_t)((b << 2) + h) * QV4;
        for (int i = tid; i < QV4; i += TPB) s4[i] = gb[i];
    }

    int d  = ray % NDET;
    int pb = ray / NDET;
    int p  = pb & (NPROJ - 1);

    const float dt = 1.4142135623730951f;              // diag / NS = sqrt(2)
    const float t0 = 219.68777079743137f;              // SID - diag/2 + 0.5*dt

    float theta = (float)p * (6.283185307179586f / (float)NPROJ);
    float st, ct;
    __sincosf(theta, &st, &ct);

    float srcx = -400.0f * ct;
    float srcy = -400.0f * st;
    float off  = ((float)d - 191.5f) * 1.2f;
    float rx   = fmaf(800.0f, ct, -off * st);
    float ry   = fmaf(800.0f, st,  off * ct);
    float n2   = rx * rx + ry * ry;
    float rn   = rsqrtf(n2);
    rn = rn * (1.5f - 0.5f * n2 * rn * rn);            // one Newton step
    rx *= rn;
    ry *= rn;

    // padded-texture coords: X(s)=bxu+s*sx, Y(s)=byu+s*sy, valid in [0,257)
    float bxu = fmaf(t0, rx, srcx) + 128.5f;
    float byu = fmaf(t0, ry, srcy) + 128.5f;
    float sx  = dt * rx;
    float sy  = dt * ry;

    // global guard-free interval (EPS-shrunk; dropped border samples ~0 weight)
    const float EPS = 2e-3f;
    float sxs = (fabsf(sx) < 1e-9f) ? copysignf(1e-9f, sx) : sx;
    float sys = (fabsf(sy) < 1e-9f) ? copysignf(1e-9f, sy) : sy;
    float isx = 1.0f / sxs;
    float isy = 1.0f / sys;
    float ax0 = (0.0f - bxu) * isx, ax1 = (257.0f - bxu) * isx;
    float ay0 = (0.0f - byu) * isy, ay1 = (257.0f - byu) * isy;
    float lo  = fmaxf(fminf(ax0, ax1), fminf(ay0, ay1)) + EPS;
    float hi  = fminf(fmaxf(ax0, ax1), fmaxf(ay0, ay1)) - EPS;
    lo = fminf(fmaxf(lo, -1.0f), 300.0f);
    hi = fminf(fmaxf(hi, -1.0f), 300.0f);
    int slo = max(0,      (int)ceilf(lo));
    int shi = min(NS - 1, (int)floorf(hi));

    // exact complementary 4-way split (identical float ops in all 4 blocks)
    float t1 = fminf(fmaxf((65.0f  - byu) * isy, -2.0f), 300.0f);
    float t2 = fminf(fmaxf((129.0f - byu) * isy, -2.0f), 300.0f);
    float t3 = fminf(fmaxf((193.0f - byu) * isy, -2.0f), 300.0f);
    bool pos = (sys > 0.0f);
    int myLo = slo, myHi = shi;
    if (pos) {                                         // Y increasing with s
        int k1 = (int)ceilf(t1), k2 = (int)ceilf(t2), k3 = (int)ceilf(t3);
        if (h == 0)      {                       myHi = min(shi, k1 - 1); }
        else if (h == 1) { myLo = max(slo, k1);  myHi = min(shi, k2 - 1); }
        else if (h == 2) { myLo = max(slo, k2);  myHi = min(shi, k3 - 1); }
        else             { myLo = max(slo, k3);                           }
    } else {                                           // Y decreasing with s
        int k1 = (int)floorf(t1), k2 = (int)floorf(t2), k3 = (int)floorf(t3);
        if (h == 0)      { myLo = max(slo, k1 + 1);                       }
        else if (h == 1) { myLo = max(slo, k2 + 1); myHi = min(shi, k1);  }
        else if (h == 2) { myLo = max(slo, k3 + 1); myHi = min(shi, k2);  }
        else             {                          myHi = min(shi, k3);  }
    }
    float byl = byu - (float)c_base[h];                // local staged-row coords

    __syncthreads();                                   // LDS quarter ready

    float acc = 0.0f;
    float sf  = (float)myLo;
    for (int s = myLo; s <= myHi; ++s) {
        float X = fmaf(sf, sx, bxu);
        float Y = fmaf(sf, sy, byl);
        sf += 1.0f;
        float Xf = floorf(X);
        float Yf = floorf(Y);
        float wx = X - Xf;
        float wy = Y - Yf;
        int ux  = (int)Xf;                             // in [0,256]
        int uyl = (int)Yf;                             // staged row in [0,67]
        int addr = uyl * QST + ux;
        uint V0 = sV[addr];                            // merge -> ds_read2_b32
        uint V1 = sV[addr + 1];
        hvec2 hw = __builtin_bit_cast(hvec2, __builtin_amdgcn_cvt_pkrtz(1.0f - wy, wy));
        hvec2 a0 = __builtin_bit_cast(hvec2, V0);      // {v(y0,x0), v(y1,x0)}
        hvec2 a1 = __builtin_bit_cast(hvec2, V1);      // {v(y0,x1), v(y1,x1)}
        float col0 = __builtin_amdgcn_fdot2(a0, hw, 0.0f, false);
        float col1 = __builtin_amdgcn_fdot2(a1, hw, 0.0f, false);
        acc = fmaf(wx, col1 - col0, acc + col0);
    }
    if (myLo <= myHi) atomicAdd(&out[ray], acc * dt);
}

extern "C" void kernel_launch(void* const* d_in, const int* in_sizes, int n_in,
                              void* d_out, int out_size, void* d_ws, size_t ws_size,
                              hipStream_t stream) {
    const float* x = (const float*)d_in[0];
    float* out     = (float*)d_out;
    uint* tex      = (uint*)d_ws;                      // NBATCH*4*QDWP*4 = 572 KB

    hipMemsetAsync(out, 0, (size_t)out_size * sizeof(float), stream);

    int ndw = NBATCH * 4 * QDWP;                       // 142976
    pad_build_kernel<<<(ndw + 255) / 256, 256, 0, stream>>>(x, tex);

    // 1024 blocks = 256 ray-groups x 4 y-quarters; 2 blocks/CU co-resident
    fanproj_kernel<<<1024, TPB, 0, stream>>>((const uint4*)tex, out);
}

// Round 11
// 89.342 us; speedup vs baseline: 1.0573x; 1.0573x over previous
//
#include <hip/hip_runtime.h>
#include <hip/hip_fp16.h>

#define VOL    256
#define NPROJ  256
#define NDET   384
#define NS     256
#define PROW   129                 // texture row stride in DWORDS (258 halves)
#define PHR    132                 // rows staged per half (incl. margin)
#define PHD    (PHR * PROW)        // 17028 dwords = 68,112 B per half
#define PH4    (PHD / 4)           // 4257 uint4
#define ROWB   126                 // global row base of half h=1
#define NBATCH 2
#define TPB    768                 // 12 waves; 512 blocks -> 2 blocks/CU, 24 waves

typedef _Float16 hvec2 __attribute__((ext_vector_type(2)));

#if defined(__has_builtin)
#if __has_builtin(__builtin_amdgcn_fdot2)
#define HAS_FDOT2 1
#endif
#endif

// Half-texture builder (identical to round-9's verified builder):
//   dst[((b*2)+h)*PHD + rowl*PROW + q] = half2{ P(uy,2q), P(uy,2q+1) },
//   uy = rowl + h*ROWB,  P(uy,ux) = img[uy-1][ux-1], zero outside.
__global__ void pad_build_kernel(const float* __restrict__ src, uint* __restrict__ dst) {
    int idx = blockIdx.x * blockDim.x + threadIdx.x;   // over NBATCH*2*PHD
    if (idx >= NBATCH * 2 * PHD) return;
    int bh   = idx / PHD;                              // b*2+h
    int dd   = idx - bh * PHD;
    int rowl = dd / PROW;
    int q    = dd - rowl * PROW;
    int uy   = rowl + (bh & 1) * ROWB;
    int r    = uy - 1;
    int c0   = 2 * q - 1;
    const float* im = src + ((bh >> 1) << 16);
    float v0 = 0.0f, v1 = 0.0f;
    if ((unsigned)r < 256u) {
        const float* rp = im + (r << 8);
        if ((unsigned)c0 < 256u)       v0 = rp[c0];
        if ((unsigned)(c0 + 1) < 256u) v1 = rp[c0 + 1];
    }
    __half2 h2 = __floats2half2_rn(v0, v1);
    dst[idx] = *reinterpret_cast<uint*>(&h2);
}

// Two blocks per 768-ray group: h=0 handles Y<129 (rows 0..131 staged),
// h=1 handles Y>=129 (rows 126..257). Inner loop unrolled x2 with dual
// accumulators for ILP/MLP. Partials atomicAdd'ed into zeroed out.
__global__ __launch_bounds__(TPB) void fanproj_kernel(const uint4* __restrict__ G,
                                                      float* __restrict__ out) {
    __shared__ uint4 s4[PH4];                          // 68,112 B -> 2 blocks/CU
    const uint* sImg = reinterpret_cast<const uint*>(s4);

    int tid = threadIdx.x;
    int h   = blockIdx.x & 1;
    int grp = blockIdx.x >> 1;
    int ray = grp * TPB + tid;                         // b*P*D + p*D + d
    int b   = grp >> 7;                                // 128 groups per batch

    // contiguous uint4 stage of this (batch, half) texture
    {
        const uint4* gb = G + (size_t)((b << 1) + h) * PH4;
        for (int i = tid; i < PH4; i += TPB) s4[i] = gb[i];
    }

    int d  = ray % NDET;
    int pb = ray / NDET;
    int p  = pb & (NPROJ - 1);

    const float dt = 1.4142135623730951f;              // diag / NS = sqrt(2)
    const float t0 = 219.68777079743137f;              // SID - diag/2 + 0.5*dt

    float theta = (float)p * (6.283185307179586f / (float)NPROJ);
    float st, ct;
    __sincosf(theta, &st, &ct);

    float srcx = -400.0f * ct;
    float srcy = -400.0f * st;
    float off  = ((float)d - 191.5f) * 1.2f;
    float rx   = fmaf(800.0f, ct, -off * st);
    float ry   = fmaf(800.0f, st,  off * ct);
    float n2   = rx * rx + ry * ry;
    float rn   = rsqrtf(n2);
    rn = rn * (1.5f - 0.5f * n2 * rn * rn);            // one Newton step
    rx *= rn;
    ry *= rn;

    // padded-texture coords: X(s) = bxu + s*sx, valid when X,Y in [0,257)
    float bxu = fmaf(t0, rx, srcx) + 128.5f;
    float byu = fmaf(t0, ry, srcy) + 128.5f;
    float sx  = dt * rx;
    float sy  = dt * ry;

    // global guard-free interval (EPS-shrunk; border samples ~zero weight)
    const float EPS = 2e-3f;
    float sxs = (fabsf(sx) < 1e-9f) ? copysignf(1e-9f, sx) : sx;
    float sys = (fabsf(sy) < 1e-9f) ? copysignf(1e-9f, sy) : sy;
    float isx = 1.0f / sxs;
    float isy = 1.0f / sys;
    float ax0 = (0.0f - bxu) * isx, ax1 = (257.0f - bxu) * isx;
    float ay0 = (0.0f - byu) * isy, ay1 = (257.0f - byu) * isy;
    float lo  = fmaxf(fminf(ax0, ax1), fminf(ay0, ay1)) + EPS;
    float hi  = fminf(fmaxf(ax0, ax1), fmaxf(ay0, ay1)) - EPS;
    lo = fminf(fmaxf(lo, -1.0f), 300.0f);
    hi = fminf(fmaxf(hi, -1.0f), 300.0f);
    int slo = max(0,      (int)ceilf(lo));
    int shi = min(NS - 1, (int)floorf(hi));

    // exact complementary split at Y = 129 (identical float ops in both blocks)
    float tS = (129.0f - byu) * isy;
    tS = fminf(fmaxf(tS, -2.0f), 300.0f);
    int  kUp = (int)ceilf(tS);                         // split when sy > 0
    int  kDn = (int)floorf(tS) + 1;                    // split when sy < 0
    bool pos = (sys > 0.0f);
    int myLo, myHi;
    if (h == 0) {                                      // low-Y half
        myLo = pos ? slo : max(slo, kDn);
        myHi = pos ? min(shi, kUp - 1) : shi;
    } else {                                           // high-Y half
        myLo = pos ? max(slo, kUp) : slo;
        myHi = pos ? shi : min(shi, kDn - 1);
    }
    if (h) byu -= (float)ROWB;                         // local-row coordinates

    __syncthreads();                                   // LDS half-image ready

#ifdef HAS_FDOT2
#define SAMPLE(SF, ACC) do {                                                  \
        float X = fmaf((SF), sx, bxu);                                        \
        float Y = fmaf((SF), sy, byu);                                        \
        float Xf = floorf(X);                                                 \
        float Yf = floorf(Y);                                                 \
        float wx = X - Xf;                                                    \
        float wy = Y - Yf;                                                    \
        int ux = (int)Xf;                                                     \
        int uy = (int)Yf;                                                     \
        int base = uy * PROW + (ux >> 1);                                     \
        uint d0 = sImg[base];                                                 \
        uint d1 = sImg[base + 1];                                             \
        uint d2 = sImg[base + PROW];                                          \
        uint d3 = sImg[base + PROW + 1];                                      \
        unsigned sh = (unsigned)(ux & 1) << 4;                                \
        uint tw = __builtin_amdgcn_alignbit(d1, d0, sh);                      \
        uint bw = __builtin_amdgcn_alignbit(d3, d2, sh);                      \
        hvec2 hx = __builtin_bit_cast(hvec2,                                  \
                       __builtin_amdgcn_cvt_pkrtz(1.0f - wx, wx));            \
        hvec2 tv = __builtin_bit_cast(hvec2, tw);                             \
        hvec2 bv = __builtin_bit_cast(hvec2, bw);                             \
        float top = __builtin_amdgcn_fdot2(tv, hx, 0.0f, false);              \
        float bot = __builtin_amdgcn_fdot2(bv, hx, 0.0f, false);              \
        (ACC) = fmaf(wy, bot - top, (ACC) + top);                             \
    } while (0)
#else
#define SAMPLE(SF, ACC) do {                                                  \
        float X = fmaf((SF), sx, bxu);                                        \
        float Y = fmaf((SF), sy, byu);                                        \
        float Xf = floorf(X);                                                 \
        float Yf = floorf(Y);                                                 \
        float wx = X - Xf;                                                    \
        float wy = Y - Yf;                                                    \
        int ux = (int)Xf;                                                     \
        int uy = (int)Yf;                                                     \
        int base = uy * PROW + (ux >> 1);                                     \
        uint d0 = sImg[base];                                                 \
        uint d1 = sImg[base + 1];                                             \
        uint d2 = sImg[base + PROW];                                          \
        uint d3 = sImg[base + PROW + 1];                                      \
        unsigned sh = (unsigned)(ux & 1) << 4;                                \
        uint tw = __builtin_amdgcn_alignbit(d1, d0, sh);                      \
        uint bw = __builtin_amdgcn_alignbit(d3, d2, sh);                      \
        __half2 ht = *reinterpret_cast<__half2*>(&tw);                        \
        __half2 hb = *reinterpret_cast<__half2*>(&bw);                        \
        float2 rt = __half22float2(ht);                                       \
        float2 rb = __half22float2(hb);                                       \
        float top = fmaf(wx, rt.y - rt.x, rt.x);                              \
        float bot = fmaf(wx, rb.y - rb.x, rb.x);                              \
        (ACC) = fmaf(wy, bot - top, (ACC) + top);                             \
    } while (0)
#endif

    int n = myHi - myLo + 1;
    n = max(n, 0);
    float acc0 = 0.0f, acc1 = 0.0f;
    float sf = (float)myLo;
    int npair = n >> 1;
    for (int i = 0; i < npair; ++i) {                  // 2 independent chains
        SAMPLE(sf,        acc0);
        SAMPLE(sf + 1.0f, acc1);
        sf += 2.0f;
    }
    if (n & 1) SAMPLE(sf, acc0);
#undef SAMPLE

    float acc = acc0 + acc1;
    if (n > 0) atomicAdd(&out[ray], acc * dt);
}

extern "C" void kernel_launch(void* const* d_in, const int* in_sizes, int n_in,
                              void* d_out, int out_size, void* d_ws, size_t ws_size,
                              hipStream_t stream) {
    const float* x = (const float*)d_in[0];
    float* out     = (float*)d_out;
    uint* hpad     = (uint*)d_ws;                      // NBATCH*2*PHD*4 = 272 KB

    hipMemsetAsync(out, 0, (size_t)out_size * sizeof(float), stream);

    int ndw = NBATCH * 2 * PHD;                        // 68112
    pad_build_kernel<<<(ndw + 255) / 256, 256, 0, stream>>>(x, hpad);

    // 512 blocks = 256 ray-groups x 2 y-halves; 2 blocks/CU co-resident
    fanproj_kernel<<<512, TPB, 0, stream>>>((const uint4*)hpad, out);
}